// Round 5
// baseline (131.766 us; speedup 1.0000x reference)
//
#include <hip/hip_runtime.h>

#define N 1024
#define F 32
#define H 64
#define EA 8

// pack two f32 into one u32 of bf16s (round-to-nearest-ish via +0x8000)
__device__ __forceinline__ unsigned pack_bf16x2(float a, float b) {
    unsigned ua = __float_as_uint(a) + 0x8000u;
    unsigned ub = __float_as_uint(b) + 0x8000u;
    return (ua >> 16) | (ub & 0xffff0000u);
}

// Kernel 1: sv[v,h] = b[h] + sum_f X[v,f]*(W[f,h]-W[32+f,h]); nb[v,h] = sum_f X[v,f]*W[32+f,h]
// Also zeroes out[]. One wave per v; lane = h.
__global__ __launch_bounds__(256) void precompute_terms(
    const float* __restrict__ X, const float* __restrict__ W, const float* __restrict__ b,
    float* __restrict__ sv, float* __restrict__ nb, float* __restrict__ out)
{
    const int lane = threadIdx.x & 63;
    const int wid  = threadIdx.x >> 6;
    const int v    = blockIdx.x * 4 + wid;

    float4 xr[8];
    const float4* xp = (const float4*)(X + (size_t)v * F);
#pragma unroll
    for (int i = 0; i < 8; ++i) xr[i] = xp[i];
    const float* xf = (const float*)xr;

    float s = b[lane];
    float n = 0.f;
#pragma unroll
    for (int f = 0; f < F; ++f) {
        float ws = W[f * H + lane];
        float wd = W[(F + f) * H + lane];
        s = fmaf(xf[f], ws - wd, s);
        n = fmaf(xf[f], wd, n);
    }
    const int idx = v * H + lane;
    sv[idx]  = s;
    nb[idx]  = n;
    out[idx] = 0.f;
}

// Kernel 2: wave = 64 h-channels (lane=h), 2 v-rows per wave, one 64-w chunk.
// E rows are LANE-RESIDENT (lane owns w=wbase+lane, bf16-packed, 4 u32/row).
// Per j: v_readlane broadcasts E -> SGPR; scalar-pipe bf16 unpack; fma(sgpr,vgpr,vgpr).
// Zero LDS. Masks via __ballot SGPR pairs. nb coalesced per-j (L2-hot).
// 8192 wave-tasks = 2048 blocks x 4 waves -> 32 waves/CU.
__global__ __launch_bounds__(256) void edge_aggregate(
    const int* __restrict__ A, const float* __restrict__ Edge, const float* __restrict__ W,
    const float* __restrict__ sv, const float* __restrict__ nb, float* __restrict__ out)
{
    const int lane  = threadIdx.x & 63;
    const int wid   = threadIdx.x >> 6;
    const int task  = blockIdx.x * 4 + wid;   // 0..8191
    const int vpair = task >> 4;              // 0..511
    const int chunk = task & 15;              // 0..15
    const int v0    = vpair * 2;
    const int v1    = v0 + 1;
    const int wbase = chunk * 64;

    // We column for this lane's h
    float wc[EA];
#pragma unroll
    for (int e = 0; e < EA; ++e) wc[e] = W[(2 * F + e) * H + lane];

    const float s0 = sv[v0 * H + lane];
    const float s1 = sv[v1 * H + lane];

    // lane-resident E rows (w = wbase+lane): 32B coalesced per lane, pack to bf16
    const float* er0 = Edge + ((size_t)v0 * N + wbase + lane) * EA;
    const float* er1 = Edge + ((size_t)v1 * N + wbase + lane) * EA;
    const float4 ea0 = *(const float4*)er0;
    const float4 eb0 = *(const float4*)(er0 + 4);
    const float4 ea1 = *(const float4*)er1;
    const float4 eb1 = *(const float4*)(er1 + 4);
    unsigned ep0[4] = { pack_bf16x2(ea0.x, ea0.y), pack_bf16x2(ea0.z, ea0.w),
                        pack_bf16x2(eb0.x, eb0.y), pack_bf16x2(eb0.z, eb0.w) };
    unsigned ep1[4] = { pack_bf16x2(ea1.x, ea1.y), pack_bf16x2(ea1.z, ea1.w),
                        pack_bf16x2(eb1.x, eb1.y), pack_bf16x2(eb1.z, eb1.w) };

    // adjacency masks -> wave-uniform 64-bit SGPR pairs
    const unsigned long long m0 = __ballot(A[(size_t)v0 * N + wbase + lane] != 0);
    const unsigned long long m1 = __ballot(A[(size_t)v1 * N + wbase + lane] != 0);

    const float* nbp = nb + (size_t)wbase * H + lane;

    float acc0 = 0.f, acc1 = 0.f;

    for (int jo = 0; jo < 8; ++jo) {          // runtime outer: bounds VGPR pressure
#pragma unroll
        for (int jj = 0; jj < 8; ++jj) {      // unrolled: batches nb loads
            const int j = jo * 8 + jj;
            const float nbv = nbp[j * H];     // coalesced 256B, L2-hot
            float t0 = s0 + nbv;
            float t1 = s1 + nbv;
#pragma unroll
            for (int q = 0; q < 4; ++q) {
                const unsigned p0 = (unsigned)__builtin_amdgcn_readlane((int)ep0[q], j);
                const unsigned p1 = (unsigned)__builtin_amdgcn_readlane((int)ep1[q], j);
                // bf16 halves ARE f32 when placed in the high 16 bits (scalar-pipe ops)
                t0 = fmaf(__uint_as_float(p0 << 16),         wc[2 * q],     t0);
                t0 = fmaf(__uint_as_float(p0 & 0xffff0000u), wc[2 * q + 1], t0);
                t1 = fmaf(__uint_as_float(p1 << 16),         wc[2 * q],     t1);
                t1 = fmaf(__uint_as_float(p1 & 0xffff0000u), wc[2 * q + 1], t1);
            }
            acc0 += ((m0 >> j) & 1ull) ? fmaxf(t0, 0.f) : 0.f;
            acc1 += ((m1 >> j) & 1ull) ? fmaxf(t1, 0.f) : 0.f;
        }
    }

    unsafeAtomicAdd(&out[v0 * H + lane], acc0);
    unsafeAtomicAdd(&out[v1 * H + lane], acc1);
}

extern "C" void kernel_launch(void* const* d_in, const int* in_sizes, int n_in,
                              void* d_out, int out_size, void* d_ws, size_t ws_size,
                              hipStream_t stream) {
    const int*   A    = (const int*)d_in[0];
    const float* X    = (const float*)d_in[1];
    const float* Edge = (const float*)d_in[2];
    const float* W    = (const float*)d_in[3];
    const float* b    = (const float*)d_in[4];
    float* out = (float*)d_out;

    float* sv = (float*)d_ws;
    float* nb = sv + N * H;

    precompute_terms<<<dim3(256), dim3(256), 0, stream>>>(X, W, b, sv, nb, out);
    edge_aggregate<<<dim3(2048), dim3(256), 0, stream>>>(A, Edge, W, sv, nb, out);
}

// Round 6
// 104.689 us; speedup vs baseline: 1.2586x; 1.2586x over previous
//
#include <hip/hip_runtime.h>
#include <hip/hip_bf16.h>

#define N 1024
#define F 32
#define H 64
#define EA 8

typedef __attribute__((ext_vector_type(8))) short bf16x8;    // 8 bf16 in 4 VGPRs
typedef __attribute__((ext_vector_type(16))) float f32x16;   // MFMA C/D

union FragAB { bf16x8 v; unsigned u[4]; };

// pack two f32 -> one u32 holding (bf16(a) lo, bf16(b) hi), RNE
__device__ __forceinline__ unsigned pk(float a, float b) {
    union { __hip_bfloat162 h; unsigned u; } c;
    c.h = __float22bfloat162_rn(float2{a, b});
    return c.u;
}

// Kernel 1: sv[v,h] = b[h] + sum_f X[v,f]*(W[f,h]-W[32+f,h]); nb[v,h] = sum_f X[v,f]*W[32+f,h]
// Also zeroes out[]. One wave per v; lane = h.
__global__ __launch_bounds__(256) void precompute_terms(
    const float* __restrict__ X, const float* __restrict__ W, const float* __restrict__ b,
    float* __restrict__ sv, float* __restrict__ nb, float* __restrict__ out)
{
    const int lane = threadIdx.x & 63;
    const int wid  = threadIdx.x >> 6;
    const int v    = blockIdx.x * 4 + wid;

    float4 xr[8];
    const float4* xp = (const float4*)(X + (size_t)v * F);
#pragma unroll
    for (int i = 0; i < 8; ++i) xr[i] = xp[i];
    const float* xf = (const float*)xr;

    float s = b[lane];
    float n = 0.f;
#pragma unroll
    for (int f = 0; f < F; ++f) {
        float ws = W[f * H + lane];
        float wd = W[(F + f) * H + lane];
        s = fmaf(xf[f], ws - wd, s);
        n = fmaf(xf[f], wd, n);
    }
    const int idx = v * H + lane;
    sv[idx]  = s;
    nb[idx]  = n;
    out[idx] = 0.f;
}

// Kernel 2: MFMA 32x32x16 bf16. Per MFMA: M=32 w's, N=32 h's, K=16:
//   k=0..7  : E[v, w, e] (A, lanes<32) x We[e, h] (B, lanes<32)
//   k=8     : 1.0 (A) x sv[v, h] (B)           -> sv folded in
//   k=9     : (mask?0:-1) (A) x 1e30 (B)       -> masked rows -> -1e30 -> relu 0
//   C-init  : nb[w, h] in C-layout (f32)       -> nb folded in
// Wave owns a 32-w tile x 64 h (2 MFMAs/v), loops 8 v. Block = 4 waves = 128 w.
// Grid: 128 v-chunks x 8 w-quads = 1024 blocks. LDS block-reduce, fan-in-8 atomics.
__global__ __launch_bounds__(256, 4) void edge_mfma(
    const int* __restrict__ A, const float* __restrict__ Edge, const float* __restrict__ W,
    const float* __restrict__ sv, const float* __restrict__ nb, float* __restrict__ out)
{
    const int lane = threadIdx.x & 63;
    const int wid  = threadIdx.x >> 6;
    const int lg   = lane >> 5;          // k-octet group (0: k=0-7, 1: k=8-15)
    const int ln   = lane & 31;          // row (A) / col (B,C) index
    const int wq   = blockIdx.x & 7;
    const int vch  = blockIdx.x >> 3;
    const int wbase = wq * 128 + wid * 32;
    const int vbase = vch * 8;

    __shared__ float red[8][64];
    for (int i = threadIdx.x; i < 512; i += 256) ((float*)red)[i] = 0.f;

    // B static part: k=0..7 rows = We[e][h] in lanes<32 (j-th bf16 = k=oct*8+j)
    FragAB bfr[2];
#pragma unroll
    for (int half = 0; half < 2; ++half) {
        const int n = half * 32 + ln;
#pragma unroll
        for (int q = 0; q < 4; ++q) {
            unsigned we = pk(W[(2 * F + 2 * q) * H + n], W[(2 * F + 2 * q + 1) * H + n]);
            bfr[half].u[q] = (lg == 0) ? we : 0u;
        }
    }

    // C-init = nb in MFMA C-layout: row = (r&3) + 8*(r>>2) + 4*lg, col = ln (+32*half)
    f32x16 cnb[2];
#pragma unroll
    for (int half = 0; half < 2; ++half)
#pragma unroll
        for (int r = 0; r < 16; ++r) {
            const int row = (r & 3) + 8 * (r >> 2) + 4 * lg;
            cnb[half][r] = nb[(size_t)(wbase + row) * H + half * 32 + ln];
        }

    __syncthreads();   // LDS zero done

    for (int vi = 0; vi < 8; ++vi) {
        const int v = vbase + vi;

        // A fragment
        FragAB afr;
        if (lg == 0) {
            // row ln's E attrs, k=0..7: coalesced 1KB across lanes 0-31
            const float4* ep = (const float4*)(Edge + ((size_t)v * N + wbase + ln) * EA);
            const float4 e0 = ep[0];
            const float4 e1 = ep[1];
            afr.u[0] = pk(e0.x, e0.y); afr.u[1] = pk(e0.z, e0.w);
            afr.u[2] = pk(e1.x, e1.y); afr.u[3] = pk(e1.z, e1.w);
        } else {
            // k=8 -> 1.0 (sv multiplier); k=9 -> mask?0:-1 (BIG_NEG penalty)
            const int am = A[(size_t)v * N + wbase + ln];
            afr.u[0] = am ? 0x00003f80u : 0xbf803f80u;
            afr.u[1] = 0u; afr.u[2] = 0u; afr.u[3] = 0u;
        }

        // B per-v slots: lanes>=32 reg0 = (bf16(1e30) hi | bf16(sv[v,n]) lo)
        FragAB b0 = bfr[0], b1 = bfr[1];
        if (lg == 1) {
            b0.u[0] = pk(sv[(size_t)v * H + ln],      1e30f);
            b1.u[0] = pk(sv[(size_t)v * H + 32 + ln], 1e30f);
        }

        const f32x16 d0 = __builtin_amdgcn_mfma_f32_32x32x16_bf16(afr.v, b0.v, cnb[0], 0, 0, 0);
        float p0 = 0.f;
#pragma unroll
        for (int r = 0; r < 16; ++r) p0 += fmaxf(d0[r], 0.f);

        const f32x16 d1 = __builtin_amdgcn_mfma_f32_32x32x16_bf16(afr.v, b1.v, cnb[1], 0, 0, 0);
        float p1 = 0.f;
#pragma unroll
        for (int r = 0; r < 16; ++r) p1 += fmaxf(d1[r], 0.f);

        // 2 lanes per address (lg pair) -> 2-way LDS atomic, free per m136
        atomicAdd(&red[vi][ln], p0);
        atomicAdd(&red[vi][32 + ln], p1);
    }

    __syncthreads();
    for (int i = threadIdx.x; i < 512; i += 256) {
        const int vi = i >> 6, h = i & 63;
        unsafeAtomicAdd(&out[(size_t)(vbase + vi) * H + h], red[vi][h]);
    }
}

extern "C" void kernel_launch(void* const* d_in, const int* in_sizes, int n_in,
                              void* d_out, int out_size, void* d_ws, size_t ws_size,
                              hipStream_t stream) {
    const int*   A    = (const int*)d_in[0];
    const float* X    = (const float*)d_in[1];
    const float* Edge = (const float*)d_in[2];
    const float* W    = (const float*)d_in[3];
    const float* b    = (const float*)d_in[4];
    float* out = (float*)d_out;

    float* sv = (float*)d_ws;
    float* nb = sv + N * H;

    precompute_terms<<<dim3(256), dim3(256), 0, stream>>>(X, W, b, sv, nb, out);
    edge_mfma<<<dim3(1024), dim3(256), 0, stream>>>(A, Edge, W, sv, nb, out);
}

// Round 7
// 89.584 us; speedup vs baseline: 1.4709x; 1.1686x over previous
//
#include <hip/hip_runtime.h>
#include <hip/hip_bf16.h>

#define N 1024
#define F 32
#define H 64
#define EA 8

typedef __attribute__((ext_vector_type(8))) short bf16x8;    // 8 bf16 in 4 VGPRs
typedef __attribute__((ext_vector_type(16))) float f32x16;   // MFMA C/D

union FragAB { bf16x8 v; unsigned u[4]; };

// pack two f32 -> one u32 (bf16(a) lo, bf16(b) hi), RNE
__device__ __forceinline__ unsigned pk(float a, float b) {
    union { __hip_bfloat162 h; unsigned u; } c;
    c.h = __float22bfloat162_rn(float2{a, b});
    return c.u;
}

// Kernel 1: sv[v,h] = b[h] + sum_f X[v,f]*(W[f,h]-W[32+f,h]); nb[v,h] = sum_f X[v,f]*W[32+f,h]
// Also zeroes out[]. One wave per v; lane = h.
__global__ __launch_bounds__(256) void precompute_terms(
    const float* __restrict__ X, const float* __restrict__ W, const float* __restrict__ b,
    float* __restrict__ sv, float* __restrict__ nb, float* __restrict__ out)
{
    const int lane = threadIdx.x & 63;
    const int wid  = threadIdx.x >> 6;
    const int v    = blockIdx.x * 4 + wid;

    float4 xr[8];
    const float4* xp = (const float4*)(X + (size_t)v * F);
#pragma unroll
    for (int i = 0; i < 8; ++i) xr[i] = xp[i];
    const float* xf = (const float*)xr;

    float s = b[lane];
    float n = 0.f;
#pragma unroll
    for (int f = 0; f < F; ++f) {
        float ws = W[f * H + lane];
        float wd = W[(F + f) * H + lane];
        s = fmaf(xf[f], ws - wd, s);
        n = fmaf(xf[f], wd, n);
    }
    const int idx = v * H + lane;
    sv[idx]  = s;
    nb[idx]  = n;
    out[idx] = 0.f;
}

// Kernel 2: MFMA 32x32x16 bf16, branchless + prefetched.
//   k=0..7 : E[v,w,e] x We[e,h];  k=8: 1.0 x sv[v,h];  k=9: (mask?0:-1) x 1e30
//   C-init = nb[w,h] in C-layout. Wave = 32-w tile x 64 h (2 MFMAs/v), loops 8 v.
// All loads issued by all 64 lanes (redundant halves, coalesced); fragment roles
// selected by cndmask -> no exec-mask branches, compiler can pipeline freely.
// Partials via plain ds_write (conflict-free), one block reduce, fan-in-8 atomics.
__global__ __launch_bounds__(256, 4) void edge_mfma(
    const int* __restrict__ A, const float* __restrict__ Edge, const float* __restrict__ W,
    const float* __restrict__ sv, const float* __restrict__ nb, float* __restrict__ out)
{
    const int lane = threadIdx.x & 63;
    const int wid  = threadIdx.x >> 6;
    const int lg   = lane >> 5;          // k-octet group (0: k=0-7, 1: k=8-15)
    const int ln   = lane & 31;          // A-row / B,C-col index
    const int wq   = blockIdx.x & 7;
    const int vch  = blockIdx.x >> 3;
    const int wbase = wq * 128 + wid * 32;
    const int vbase = vch * 8;

    __shared__ float part[4][2][8][64];  // [wid][lg][vi][col] = 16 KB

    // B static: We[e][h] packed in lanes<32 k-octet; zeros in k-octet 1
    FragAB bfr[2];
#pragma unroll
    for (int half = 0; half < 2; ++half) {
        const int n = half * 32 + ln;
#pragma unroll
        for (int q = 0; q < 4; ++q) {
            unsigned we = pk(W[(2 * F + 2 * q) * H + n], W[(2 * F + 2 * q + 1) * H + n]);
            bfr[half].u[q] = (lg == 0) ? we : 0u;
        }
    }

    // C-init = nb in MFMA C-layout: row=(r&3)+8*(r>>2)+4*lg, col=ln(+32*half)
    f32x16 cnb[2];
#pragma unroll
    for (int half = 0; half < 2; ++half)
#pragma unroll
        for (int r = 0; r < 16; ++r) {
            const int row = (r & 3) + 8 * (r >> 2) + 4 * lg;
            cnb[half][r] = nb[(size_t)(wbase + row) * H + half * 32 + ln];
        }

    // E row pointer for this lane's w (=wbase+ln); v-stride = N*EA/4 = 2048 float4
    const float4* ep = (const float4*)(Edge + ((size_t)vbase * N + wbase + ln) * EA);
    const int* ap = A + (size_t)vbase * N + wbase + ln;

    // depth-1 register prefetch
    float4 eA = ep[0];
    float4 eB = ep[1];
    int    am = ap[0];

#pragma unroll
    for (int vi = 0; vi < 8; ++vi) {
        const float4 ca = eA;
        const float4 cb = eB;
        const int   cam = am;
        if (vi < 7) {
            eA = ep[(vi + 1) * 2048];
            eB = ep[(vi + 1) * 2048 + 1];
            am = ap[(size_t)(vi + 1) * N];
        }
        const int v = vbase + vi;
        const unsigned sp0 = pk(sv[(size_t)v * H + ln],      1e30f);
        const unsigned sp1 = pk(sv[(size_t)v * H + 32 + ln], 1e30f);

        FragAB afr;
        const unsigned mpat = cam ? 0x00003f80u : 0xbf803f80u;  // k8=1.0, k9=0/-1
        afr.u[0] = (lg == 0) ? pk(ca.x, ca.y) : mpat;
        afr.u[1] = (lg == 0) ? pk(ca.z, ca.w) : 0u;
        afr.u[2] = (lg == 0) ? pk(cb.x, cb.y) : 0u;
        afr.u[3] = (lg == 0) ? pk(cb.z, cb.w) : 0u;

        FragAB b0 = bfr[0], b1 = bfr[1];
        if (lg) { b0.u[0] = sp0; b1.u[0] = sp1; }

        const f32x16 d0 = __builtin_amdgcn_mfma_f32_32x32x16_bf16(afr.v, b0.v, cnb[0], 0, 0, 0);
        const f32x16 d1 = __builtin_amdgcn_mfma_f32_32x32x16_bf16(afr.v, b1.v, cnb[1], 0, 0, 0);

        float p0 = 0.f, p1 = 0.f;
#pragma unroll
        for (int r = 0; r < 16; ++r) {
            p0 += fmaxf(d0[r], 0.f);
            p1 += fmaxf(d1[r], 0.f);
        }
        part[wid][lg][vi][ln]      = p0;   // lanes L and L+32 same bank: 2-way, free
        part[wid][lg][vi][32 + ln] = p1;
    }

    __syncthreads();
#pragma unroll
    for (int i = threadIdx.x; i < 512; i += 256) {
        const int vi = i >> 6, h = i & 63;
        float s = 0.f;
#pragma unroll
        for (int w4 = 0; w4 < 4; ++w4)
#pragma unroll
            for (int g = 0; g < 2; ++g) s += part[w4][g][vi][h];
        unsafeAtomicAdd(&out[(size_t)(vbase + vi) * H + h], s);
    }
}

extern "C" void kernel_launch(void* const* d_in, const int* in_sizes, int n_in,
                              void* d_out, int out_size, void* d_ws, size_t ws_size,
                              hipStream_t stream) {
    const int*   A    = (const int*)d_in[0];
    const float* X    = (const float*)d_in[1];
    const float* Edge = (const float*)d_in[2];
    const float* W    = (const float*)d_in[3];
    const float* b    = (const float*)d_in[4];
    float* out = (float*)d_out;

    float* sv = (float*)d_ws;
    float* nb = sv + N * H;

    precompute_terms<<<dim3(256), dim3(256), 0, stream>>>(X, W, b, sv, nb, out);
    edge_mfma<<<dim3(1024), dim3(256), 0, stream>>>(A, Edge, W, sv, nb, out);
}